// Round 7
// baseline (316.797 us; speedup 1.0000x reference)
//
#include <hip/hip_runtime.h>

#define N_NODES 50000
#define N_EDGES 800000
#define NB 196  // ceil(N_NODES / 256)

typedef unsigned int uint;

__device__ __forceinline__ ushort f2bf(float f) {
    union { float f; uint u; } v; v.f = f;
    uint r = (v.u + 0x7FFFu + ((v.u >> 16) & 1u)) >> 16;  // RNE
    return (ushort)r;
}
__device__ __forceinline__ float bf_lo(uint u) { return __uint_as_float(u << 16); }
__device__ __forceinline__ float bf_hi(uint u) { return __uint_as_float(u & 0xFFFF0000u); }

// ---------- fp32 -> bf16 table conversion (8 floats/thread) ----------
__global__ void k_tobf16(const float* __restrict__ in, uint* __restrict__ out) {
    int t = blockIdx.x * 256 + threadIdx.x;      // over N*128/8 groups
    const float4* i4 = (const float4*)in + (size_t)t * 2;
    float4 v0 = i4[0], v1 = i4[1];
    uint4 o;
    o.x = (uint)f2bf(v0.x) | ((uint)f2bf(v0.y) << 16);
    o.y = (uint)f2bf(v0.z) | ((uint)f2bf(v0.w) << 16);
    o.z = (uint)f2bf(v1.x) | ((uint)f2bf(v1.y) << 16);
    o.w = (uint)f2bf(v1.z) | ((uint)f2bf(v1.w) << 16);
    ((uint4*)out)[t] = o;
}

// ---------- degree / CSR build ----------

__global__ void k_zero(int* counts) {
    int i = blockIdx.x * 256 + threadIdx.x;
    if (i < N_NODES) counts[i] = 0;
}

__global__ void k_hist(const int* __restrict__ dst, int* __restrict__ counts) {
    int e = blockIdx.x * 256 + threadIdx.x;
    if (e < N_EDGES) atomicAdd(&counts[dst[e]], 1);
}

__global__ void k_blocksum(const int* __restrict__ counts, int* __restrict__ bsum) {
    __shared__ int lds[256];
    int t = threadIdx.x;
    int i = blockIdx.x * 256 + t;
    int v = (i < N_NODES) ? counts[i] : 0;
    lds[t] = v;
    __syncthreads();
    for (int off = 128; off > 0; off >>= 1) {
        if (t < off) lds[t] += lds[t + off];
        __syncthreads();
    }
    if (t == 0) bsum[blockIdx.x] = lds[0];
}

__global__ void k_scanb(const int* __restrict__ bsum, int* __restrict__ boff) {
    __shared__ int lds[256];
    int t = threadIdx.x;
    int v = (t < NB) ? bsum[t] : 0;
    lds[t] = v;
    __syncthreads();
    for (int off = 1; off < 256; off <<= 1) {
        int o = (t >= off) ? lds[t - off] : 0;
        __syncthreads();
        lds[t] += o;
        __syncthreads();
    }
    if (t < NB) boff[t] = lds[t] - v;  // exclusive
}

__global__ void k_scatter_rp(const int* __restrict__ counts, const int* __restrict__ boff,
                             int* __restrict__ row_ptr, int* __restrict__ fill,
                             float* __restrict__ dinv) {
    __shared__ int lds[256];
    int t = threadIdx.x;
    int i = blockIdx.x * 256 + t;
    int v = (i < N_NODES) ? counts[i] : 0;
    lds[t] = v;
    __syncthreads();
    for (int off = 1; off < 256; off <<= 1) {
        int o = (t >= off) ? lds[t - off] : 0;
        __syncthreads();
        lds[t] += o;
        __syncthreads();
    }
    if (i < N_NODES) {
        int excl = boff[blockIdx.x] + lds[t] - v;
        row_ptr[i] = excl;
        fill[i] = excl;
        dinv[i] = rsqrtf((float)(v + 1));  // +1 self-loop
    }
    if (i == 0) row_ptr[N_NODES] = N_EDGES;
}

__global__ void k_fill(const int* __restrict__ src, const int* __restrict__ dst,
                       int* __restrict__ fill, int* __restrict__ csr_src) {
    int e = blockIdx.x * 256 + threadIdx.x;
    if (e >= N_EDGES) return;
    int pos = atomicAdd(&fill[dst[e]], 1);
    csr_src[pos] = src[e];
}

// ---------- gather aggregation over bf16 table (F=128, one wave per dst) ----------
__global__ void k_gather128h(const uint* __restrict__ xh, const int* __restrict__ csr,
                             const int* __restrict__ rp, const float* __restrict__ dinv,
                             const float* __restrict__ bias, float* __restrict__ out) {
    int node = blockIdx.x * 4 + (threadIdx.x >> 6);
    int lane = threadIdx.x & 63;
    int q = lane >> 4;
    int fl = lane & 15;
    int beg = rp[node], end = rp[node + 1];
    const uint4* xb = (const uint4*)xh;  // row s = 16 uint4s
    float a[8];
    #pragma unroll
    for (int i = 0; i < 8; ++i) a[i] = 0.f;

    for (int j = beg + q; j < end; j += 8) {
        int s0 = csr[j];
        float c0 = dinv[s0];
        uint4 u = xb[(size_t)s0 * 16 + fl];
        int j1 = j + 4;
        int s1 = s0;
        float c1 = 0.f;
        if (j1 < end) { s1 = csr[j1]; c1 = dinv[s1]; }
        uint4 w = xb[(size_t)s1 * 16 + fl];
        a[0] = fmaf(c0, bf_lo(u.x), a[0]); a[1] = fmaf(c0, bf_hi(u.x), a[1]);
        a[2] = fmaf(c0, bf_lo(u.y), a[2]); a[3] = fmaf(c0, bf_hi(u.y), a[3]);
        a[4] = fmaf(c0, bf_lo(u.z), a[4]); a[5] = fmaf(c0, bf_hi(u.z), a[5]);
        a[6] = fmaf(c0, bf_lo(u.w), a[6]); a[7] = fmaf(c0, bf_hi(u.w), a[7]);
        a[0] = fmaf(c1, bf_lo(w.x), a[0]); a[1] = fmaf(c1, bf_hi(w.x), a[1]);
        a[2] = fmaf(c1, bf_lo(w.y), a[2]); a[3] = fmaf(c1, bf_hi(w.y), a[3]);
        a[4] = fmaf(c1, bf_lo(w.z), a[4]); a[5] = fmaf(c1, bf_hi(w.z), a[5]);
        a[6] = fmaf(c1, bf_lo(w.w), a[6]); a[7] = fmaf(c1, bf_hi(w.w), a[7]);
    }
    #pragma unroll
    for (int off = 16; off < 64; off <<= 1) {
        #pragma unroll
        for (int i = 0; i < 8; ++i) a[i] += __shfl_xor(a[i], off);
    }
    if (q == 0) {
        float dd = dinv[node];
        float dd2 = dd * dd;
        uint4 u = xb[(size_t)node * 16 + fl];
        float s[8] = { bf_lo(u.x), bf_hi(u.x), bf_lo(u.y), bf_hi(u.y),
                       bf_lo(u.z), bf_hi(u.z), bf_lo(u.w), bf_hi(u.w) };
        float o[8];
        #pragma unroll
        for (int i = 0; i < 8; ++i) o[i] = fmaf(dd, a[i], dd2 * s[i]);
        if (bias) {
            const float4* bb = (const float4*)bias;
            float4 b0 = bb[fl * 2], b1 = bb[fl * 2 + 1];
            o[0] += b0.x; o[1] += b0.y; o[2] += b0.z; o[3] += b0.w;
            o[4] += b1.x; o[5] += b1.y; o[6] += b1.z; o[7] += b1.w;
        }
        float4* ob = (float4*)out + (size_t)node * 32 + fl * 2;
        ob[0] = make_float4(o[0], o[1], o[2], o[3]);
        ob[1] = make_float4(o[4], o[5], o[6], o[7]);
    }
}

// ---------- GEMM: out[RPB rows][NC] = A[RPB][K] @ W[K][NC] (+ bias) ----------
// A staged row-major [RPB][BK] in LDS; A reads wave-broadcast, conflict-free.
// W software-pipelined: next k-quad's 4 float4s prefetched during current FMAs
// (W's k index advances linearly across chunk boundaries; no barrier dependency).
// Thread = 4 cols (jc) x MR rows (rc). NT = (NC/4)*(RPB/MR).
template<int K, int NC, int RPB, int MR, int BK, bool BF16OUT, int NT>
__global__ void __launch_bounds__(NT)
k_gemm(const float* __restrict__ A, const float* __restrict__ W,
       const float* __restrict__ bias, void* __restrict__ outp) {
    static_assert(NT == (NC / 4) * (RPB / MR), "thread count");
    __shared__ float lds[RPB][BK];
    const int row0 = blockIdx.x * RPB;
    const int t = threadIdx.x;
    const int jc = (t % (NC / 4)) * 4;
    const int rc = (t / (NC / 4)) * MR;

    float4 acc[MR];
    #pragma unroll
    for (int m = 0; m < MR; ++m) acc[m] = make_float4(0.f, 0.f, 0.f, 0.f);

    // prime W pipeline (k-quad 0)
    const float* wr0 = &W[jc];
    float4 w0 = *(const float4*)(wr0);
    float4 w1 = *(const float4*)(wr0 + NC);
    float4 w2 = *(const float4*)(wr0 + 2 * NC);
    float4 w3 = *(const float4*)(wr0 + 3 * NC);

    for (int k0 = 0; k0 < K; k0 += BK) {
        if (k0 > 0) __syncthreads();
        constexpr int QUADS = RPB * BK / 4;
        #pragma unroll
        for (int i = 0; i < QUADS / NT; ++i) {
            int idx = i * NT + t;
            int r = idx / (BK / 4), k4 = idx % (BK / 4);
            int rg = row0 + r;
            if (rg >= N_NODES) rg = N_NODES - 1;  // tail clamp
            *(float4*)&lds[r][k4 * 4] = *(const float4*)&A[(size_t)rg * K + k0 + k4 * 4];
        }
        __syncthreads();

        #pragma unroll 2
        for (int kk = 0; kk < BK; kk += 4) {
            // prefetch next k-quad of W (crosses chunk boundary freely)
            float4 n0 = w0, n1 = w1, n2 = w2, n3 = w3;
            int kn = k0 + kk + 4;
            if (kn < K) {
                const float* wr = &W[(size_t)kn * NC + jc];
                n0 = *(const float4*)(wr);
                n1 = *(const float4*)(wr + NC);
                n2 = *(const float4*)(wr + 2 * NC);
                n3 = *(const float4*)(wr + 3 * NC);
            }
            #pragma unroll
            for (int m = 0; m < MR; ++m) {
                float4 a = *(const float4*)&lds[rc + m][kk];  // broadcast
                acc[m].x = fmaf(a.x, w0.x, acc[m].x);
                acc[m].y = fmaf(a.x, w0.y, acc[m].y);
                acc[m].z = fmaf(a.x, w0.z, acc[m].z);
                acc[m].w = fmaf(a.x, w0.w, acc[m].w);
                acc[m].x = fmaf(a.y, w1.x, acc[m].x);
                acc[m].y = fmaf(a.y, w1.y, acc[m].y);
                acc[m].z = fmaf(a.y, w1.z, acc[m].z);
                acc[m].w = fmaf(a.y, w1.w, acc[m].w);
                acc[m].x = fmaf(a.z, w2.x, acc[m].x);
                acc[m].y = fmaf(a.z, w2.y, acc[m].y);
                acc[m].z = fmaf(a.z, w2.z, acc[m].z);
                acc[m].w = fmaf(a.z, w2.w, acc[m].w);
                acc[m].x = fmaf(a.w, w3.x, acc[m].x);
                acc[m].y = fmaf(a.w, w3.y, acc[m].y);
                acc[m].z = fmaf(a.w, w3.z, acc[m].z);
                acc[m].w = fmaf(a.w, w3.w, acc[m].w);
            }
            w0 = n0; w1 = n1; w2 = n2; w3 = n3;
        }
    }

    float4 b = make_float4(0.f, 0.f, 0.f, 0.f);
    if (bias) b = *(const float4*)&bias[jc];
    #pragma unroll
    for (int m = 0; m < MR; ++m) {
        int r = row0 + rc + m;
        if (r < N_NODES) {
            float4 o = acc[m];
            o.x += b.x; o.y += b.y; o.z += b.z; o.w += b.w;
            if constexpr (BF16OUT) {
                uint2 p;
                p.x = (uint)f2bf(o.x) | ((uint)f2bf(o.y) << 16);
                p.y = (uint)f2bf(o.z) | ((uint)f2bf(o.w) << 16);
                *(uint2*)((ushort*)outp + (size_t)r * NC + jc) = p;
            } else {
                *(float4*)((float*)outp + (size_t)r * NC + jc) = o;
            }
        }
    }
}

extern "C" void kernel_launch(void* const* d_in, const int* in_sizes, int n_in,
                              void* d_out, int out_size, void* d_ws, size_t ws_size,
                              hipStream_t stream) {
    const float* emb = (const float*)d_in[0];   // [50000][128]
    const float* W1  = (const float*)d_in[1];   // [128][256]
    const float* b1  = (const float*)d_in[2];   // [256]
    const float* W2  = (const float*)d_in[3];   // [256][128]
    const float* b2  = (const float*)d_in[4];   // [128]
    const int*   ei  = (const int*)d_in[5];     // [2][800000]
    const int* src = ei;
    const int* dst = ei + N_EDGES;

    char* ws = (char*)d_ws;
    float* dinv    = (float*)(ws);                    // 200 KB
    int*   counts  = (int*)  (ws + (256ull << 10));   // 200 KB
    int*   row_ptr = (int*)  (ws + (512ull << 10));   // 200 KB + 4
    int*   fill    = (int*)  (ws + (768ull << 10));   // 200 KB
    int*   bsum    = (int*)  (ws + (1008ull << 10));  // 784 B
    int*   boff    = (int*)  (ws + (1016ull << 10));  // 784 B
    int*   csr_src = (int*)  (ws + (1ull   << 20));   // 3.2 MB   (1..4.2 MB)
    uint*  emb_h   = (uint*) (ws + (5ull   << 20));   // 12.8 MB  (5..17.8 MB)
    uint*  x2_h    = (uint*) (ws + (18ull  << 20));   // 12.8 MB  (18..30.8 MB)
    float* agg0    = (float*)(ws + (18ull  << 20));   // 25.6 MB  (18..43.6) overlay: agg0 dead before x2_h written
    float* h       = (float*)(ws + (44ull  << 20));   // 51.2 MB  (44..95.2 MB)
    float* out     = (float*)d_out;

    // bf16 shadow of emb (independent of CSR chain)
    k_tobf16<<<N_NODES * 128 / 8 / 256, 256, 0, stream>>>(emb, emb_h);

    // CSR build + normalization (device-wide 3-stage scan)
    k_zero<<<NB, 256, 0, stream>>>(counts);
    k_hist<<<(N_EDGES + 255) / 256, 256, 0, stream>>>(dst, counts);
    k_blocksum<<<NB, 256, 0, stream>>>(counts, bsum);
    k_scanb<<<1, 256, 0, stream>>>(bsum, boff);
    k_scatter_rp<<<NB, 256, 0, stream>>>(counts, boff, row_ptr, fill, dinv);
    k_fill<<<(N_EDGES + 255) / 256, 256, 0, stream>>>(src, dst, fill, csr_src);

    // layer 1 (reordered): agg0 = Agg(emb); h = agg0 @ W1 + b1
    k_gather128h<<<12500, 256, 0, stream>>>(emb_h, csr_src, row_ptr, dinv, nullptr, agg0);
    // K=128 NC=256 RPB=64 MR=4 BK=64 -> 1024 threads, 16KB LDS
    k_gemm<128, 256, 64, 4, 64, false, 1024><<<(N_NODES + 63) / 64, 1024, 0, stream>>>(agg0, W1, b1, h);

    // layer 2: x2_h = bf16(h @ W2) ; out = Agg(x2) + b2
    // K=256 NC=128 RPB=64 MR=4 BK=64 -> 512 threads, 16KB LDS
    k_gemm<256, 128, 64, 4, 64, true, 512><<<(N_NODES + 63) / 64, 512, 0, stream>>>(h, W2, nullptr, (void*)x2_h);
    k_gather128h<<<12500, 256, 0, stream>>>(x2_h, csr_src, row_ptr, dinv, b2, out);
}

// Round 8
// 252.220 us; speedup vs baseline: 1.2560x; 1.2560x over previous
//
#include <hip/hip_runtime.h>

#define N_NODES 50000
#define N_EDGES 800000
#define NB 196  // ceil(N_NODES / 256)

typedef unsigned int uint;
typedef short bf16x8 __attribute__((ext_vector_type(8)));
typedef float f32x4 __attribute__((ext_vector_type(4)));

__device__ __forceinline__ ushort f2bf(float f) {
    union { float f; uint u; } v; v.f = f;
    uint r = (v.u + 0x7FFFu + ((v.u >> 16) & 1u)) >> 16;  // RNE
    return (ushort)r;
}
__device__ __forceinline__ float bf_lo(uint u) { return __uint_as_float(u << 16); }
__device__ __forceinline__ float bf_hi(uint u) { return __uint_as_float(u & 0xFFFF0000u); }

// ---------- fp32 -> bf16 row-major copy (8 floats/thread) ----------
__global__ void k_tobf16(const float* __restrict__ in, uint* __restrict__ out) {
    int t = blockIdx.x * 256 + threadIdx.x;
    const float4* i4 = (const float4*)in + (size_t)t * 2;
    float4 v0 = i4[0], v1 = i4[1];
    uint4 o;
    o.x = (uint)f2bf(v0.x) | ((uint)f2bf(v0.y) << 16);
    o.y = (uint)f2bf(v0.z) | ((uint)f2bf(v0.w) << 16);
    o.z = (uint)f2bf(v1.x) | ((uint)f2bf(v1.y) << 16);
    o.w = (uint)f2bf(v1.z) | ((uint)f2bf(v1.w) << 16);
    ((uint4*)out)[t] = o;
}

// ---------- W[K][N] fp32 -> Wt[N][K] bf16 (8 k-elems per thread) ----------
__global__ void k_wt(const float* __restrict__ W, uint* __restrict__ Wt, int K, int N) {
    int id = blockIdx.x * 256 + threadIdx.x;   // over N*K/8
    int kq = K / 8;
    int n = id / kq;
    int k0 = (id % kq) * 8;
    uint4 o;
    o.x = (uint)f2bf(W[(size_t)(k0 + 0) * N + n]) | ((uint)f2bf(W[(size_t)(k0 + 1) * N + n]) << 16);
    o.y = (uint)f2bf(W[(size_t)(k0 + 2) * N + n]) | ((uint)f2bf(W[(size_t)(k0 + 3) * N + n]) << 16);
    o.z = (uint)f2bf(W[(size_t)(k0 + 4) * N + n]) | ((uint)f2bf(W[(size_t)(k0 + 5) * N + n]) << 16);
    o.w = (uint)f2bf(W[(size_t)(k0 + 6) * N + n]) | ((uint)f2bf(W[(size_t)(k0 + 7) * N + n]) << 16);
    ((uint4*)Wt)[id] = o;
}

// ---------- degree / CSR build ----------

__global__ void k_zero(int* counts) {
    int i = blockIdx.x * 256 + threadIdx.x;
    if (i < N_NODES) counts[i] = 0;
}

__global__ void k_hist(const int* __restrict__ dst, int* __restrict__ counts) {
    int e = blockIdx.x * 256 + threadIdx.x;
    if (e < N_EDGES) atomicAdd(&counts[dst[e]], 1);
}

__global__ void k_blocksum(const int* __restrict__ counts, int* __restrict__ bsum) {
    __shared__ int lds[256];
    int t = threadIdx.x;
    int i = blockIdx.x * 256 + t;
    int v = (i < N_NODES) ? counts[i] : 0;
    lds[t] = v;
    __syncthreads();
    for (int off = 128; off > 0; off >>= 1) {
        if (t < off) lds[t] += lds[t + off];
        __syncthreads();
    }
    if (t == 0) bsum[blockIdx.x] = lds[0];
}

__global__ void k_scanb(const int* __restrict__ bsum, int* __restrict__ boff) {
    __shared__ int lds[256];
    int t = threadIdx.x;
    int v = (t < NB) ? bsum[t] : 0;
    lds[t] = v;
    __syncthreads();
    for (int off = 1; off < 256; off <<= 1) {
        int o = (t >= off) ? lds[t - off] : 0;
        __syncthreads();
        lds[t] += o;
        __syncthreads();
    }
    if (t < NB) boff[t] = lds[t] - v;  // exclusive
}

__global__ void k_scatter_rp(const int* __restrict__ counts, const int* __restrict__ boff,
                             int* __restrict__ row_ptr, int* __restrict__ fill,
                             float* __restrict__ dinv) {
    __shared__ int lds[256];
    int t = threadIdx.x;
    int i = blockIdx.x * 256 + t;
    int v = (i < N_NODES) ? counts[i] : 0;
    lds[t] = v;
    __syncthreads();
    for (int off = 1; off < 256; off <<= 1) {
        int o = (t >= off) ? lds[t - off] : 0;
        __syncthreads();
        lds[t] += o;
        __syncthreads();
    }
    if (i < N_NODES) {
        int excl = boff[blockIdx.x] + lds[t] - v;
        row_ptr[i] = excl;
        fill[i] = excl;
        dinv[i] = rsqrtf((float)(v + 1));  // +1 self-loop
    }
    if (i == 0) row_ptr[N_NODES] = N_EDGES;
}

__global__ void k_fill(const int* __restrict__ src, const int* __restrict__ dst,
                       int* __restrict__ fill, int* __restrict__ csr_src) {
    int e = blockIdx.x * 256 + threadIdx.x;
    if (e >= N_EDGES) return;
    int pos = atomicAdd(&fill[dst[e]], 1);
    csr_src[pos] = src[e];
}

// ---------- gather aggregation over bf16 table (F=128, one wave per dst) ----------
// OBF16: write bf16 row (for feeding MFMA GEMM); else fp32 (+bias) final output.
template<bool OBF16>
__global__ void k_gather128h(const uint* __restrict__ xh, const int* __restrict__ csr,
                             const int* __restrict__ rp, const float* __restrict__ dinv,
                             const float* __restrict__ bias, void* __restrict__ outp) {
    int node = blockIdx.x * 4 + (threadIdx.x >> 6);
    int lane = threadIdx.x & 63;
    int q = lane >> 4;
    int fl = lane & 15;
    int beg = rp[node], end = rp[node + 1];
    const uint4* xb = (const uint4*)xh;  // row s = 16 uint4s
    float a[8];
    #pragma unroll
    for (int i = 0; i < 8; ++i) a[i] = 0.f;

    for (int j = beg + q; j < end; j += 8) {
        int s0 = csr[j];
        float c0 = dinv[s0];
        uint4 u = xb[(size_t)s0 * 16 + fl];
        int j1 = j + 4;
        int s1 = s0;
        float c1 = 0.f;
        if (j1 < end) { s1 = csr[j1]; c1 = dinv[s1]; }
        uint4 w = xb[(size_t)s1 * 16 + fl];
        a[0] = fmaf(c0, bf_lo(u.x), a[0]); a[1] = fmaf(c0, bf_hi(u.x), a[1]);
        a[2] = fmaf(c0, bf_lo(u.y), a[2]); a[3] = fmaf(c0, bf_hi(u.y), a[3]);
        a[4] = fmaf(c0, bf_lo(u.z), a[4]); a[5] = fmaf(c0, bf_hi(u.z), a[5]);
        a[6] = fmaf(c0, bf_lo(u.w), a[6]); a[7] = fmaf(c0, bf_hi(u.w), a[7]);
        a[0] = fmaf(c1, bf_lo(w.x), a[0]); a[1] = fmaf(c1, bf_hi(w.x), a[1]);
        a[2] = fmaf(c1, bf_lo(w.y), a[2]); a[3] = fmaf(c1, bf_hi(w.y), a[3]);
        a[4] = fmaf(c1, bf_lo(w.z), a[4]); a[5] = fmaf(c1, bf_hi(w.z), a[5]);
        a[6] = fmaf(c1, bf_lo(w.w), a[6]); a[7] = fmaf(c1, bf_hi(w.w), a[7]);
    }
    #pragma unroll
    for (int off = 16; off < 64; off <<= 1) {
        #pragma unroll
        for (int i = 0; i < 8; ++i) a[i] += __shfl_xor(a[i], off);
    }
    if (q == 0) {
        float dd = dinv[node];
        float dd2 = dd * dd;
        uint4 u = xb[(size_t)node * 16 + fl];
        float s[8] = { bf_lo(u.x), bf_hi(u.x), bf_lo(u.y), bf_hi(u.y),
                       bf_lo(u.z), bf_hi(u.z), bf_lo(u.w), bf_hi(u.w) };
        float o[8];
        #pragma unroll
        for (int i = 0; i < 8; ++i) o[i] = fmaf(dd, a[i], dd2 * s[i]);
        if (bias) {
            const float4* bb = (const float4*)bias;
            float4 b0 = bb[fl * 2], b1 = bb[fl * 2 + 1];
            o[0] += b0.x; o[1] += b0.y; o[2] += b0.z; o[3] += b0.w;
            o[4] += b1.x; o[5] += b1.y; o[6] += b1.z; o[7] += b1.w;
        }
        if constexpr (OBF16) {
            uint4 p;
            p.x = (uint)f2bf(o[0]) | ((uint)f2bf(o[1]) << 16);
            p.y = (uint)f2bf(o[2]) | ((uint)f2bf(o[3]) << 16);
            p.z = (uint)f2bf(o[4]) | ((uint)f2bf(o[5]) << 16);
            p.w = (uint)f2bf(o[6]) | ((uint)f2bf(o[7]) << 16);
            ((uint4*)outp)[(size_t)node * 16 + fl] = p;
        } else {
            float4* ob = (float4*)outp + (size_t)node * 32 + fl * 2;
            ob[0] = make_float4(o[0], o[1], o[2], o[3]);
            ob[1] = make_float4(o[4], o[5], o[6], o[7]);
        }
    }
}

// ---------- MFMA GEMM: out[16 rows][NC] bf16 = A[16][K] bf16 @ Wt[NC][K] bf16 (+bias) ----
// Block = 256 threads = 4 waves; block owns 16 rows; wave owns NC/4 columns.
// Fragments (16x16x32): A lane: row=l&15, k=(l>>4)*8+[0..8) contiguous.
//                       B lane: col=l&15, k contiguous -> Wt row load.
//                       D lane: col=l&15, row=(l>>4)*4+e.
template<int K, int NC>
__global__ void __launch_bounds__(256)
k_gemm_mfma(const ushort* __restrict__ A, const ushort* __restrict__ Wt,
            const float* __restrict__ bias, ushort* __restrict__ out) {
    constexpr int KC = K / 32;        // k-chunks
    constexpr int TPW = NC / 64;      // 16-col tiles per wave
    const int lane = threadIdx.x & 63;
    const int wave = threadIdx.x >> 6;
    const int row0 = blockIdx.x * 16;
    const int r = row0 + (lane & 15);
    const int ksub = (lane >> 4) * 8;

    f32x4 acc[TPW];
    #pragma unroll
    for (int t = 0; t < TPW; ++t) acc[t] = (f32x4){0.f, 0.f, 0.f, 0.f};

    int col[TPW];
    #pragma unroll
    for (int t = 0; t < TPW; ++t) col[t] = (wave * TPW + t) * 16 + (lane & 15);

    #pragma unroll
    for (int kc = 0; kc < KC; ++kc) {
        bf16x8 af = *(const bf16x8*)(A + (size_t)r * K + kc * 32 + ksub);
        #pragma unroll
        for (int t = 0; t < TPW; ++t) {
            bf16x8 bf = *(const bf16x8*)(Wt + (size_t)col[t] * K + kc * 32 + ksub);
            acc[t] = __builtin_amdgcn_mfma_f32_16x16x32_bf16(af, bf, acc[t], 0, 0, 0);
        }
    }

    const int rb = row0 + (lane >> 4) * 4;
    #pragma unroll
    for (int t = 0; t < TPW; ++t) {
        float b = bias ? bias[col[t]] : 0.f;
        #pragma unroll
        for (int e = 0; e < 4; ++e) {
            out[(size_t)(rb + e) * NC + col[t]] = f2bf(acc[t][e] + b);
        }
    }
}

extern "C" void kernel_launch(void* const* d_in, const int* in_sizes, int n_in,
                              void* d_out, int out_size, void* d_ws, size_t ws_size,
                              hipStream_t stream) {
    const float* emb = (const float*)d_in[0];   // [50000][128]
    const float* W1  = (const float*)d_in[1];   // [128][256]
    const float* b1  = (const float*)d_in[2];   // [256]
    const float* W2  = (const float*)d_in[3];   // [256][128]
    const float* b2  = (const float*)d_in[4];   // [128]
    const int*   ei  = (const int*)d_in[5];     // [2][800000]
    const int* src = ei;
    const int* dst = ei + N_EDGES;

    char* ws = (char*)d_ws;
    float*  dinv    = (float*) (ws);                    // 200 KB
    int*    counts  = (int*)   (ws + (256ull << 10));   // 200 KB
    int*    row_ptr = (int*)   (ws + (512ull << 10));   // 200 KB + 4
    int*    fill    = (int*)   (ws + (768ull << 10));   // 200 KB
    int*    bsum    = (int*)   (ws + (1008ull << 10));  // 784 B
    int*    boff    = (int*)   (ws + (1016ull << 10));  // 784 B
    int*    csr_src = (int*)   (ws + (1ull << 20));     // 3.2 MB   (1..4.2)
    uint*   W1t     = (uint*)  (ws + (4352ull << 10));  // 64 KB    Wt[256][128] bf16
    uint*   W2t     = (uint*)  (ws + (4608ull << 10));  // 64 KB    Wt[128][256] bf16
    uint*   emb_h   = (uint*)  (ws + (5ull  << 20));    // 12.8 MB  (5..17.8)
    uint*   agg0_h  = (uint*)  (ws + (18ull << 20));    // 12.8 MB  (18..30.8)
    ushort* h_h     = (ushort*)(ws + (31ull << 20));    // 25.6 MB  (31..56.6)
    ushort* x2_h    = (ushort*)(ws + (57ull << 20));    // 12.8 MB  (57..69.8)
    float*  out     = (float*)d_out;

    // bf16 shadows (independent of CSR chain)
    k_tobf16<<<N_NODES * 128 / 8 / 256, 256, 0, stream>>>(emb, emb_h);
    k_wt<<<(128 * 256 / 8) / 256, 256, 0, stream>>>(W1, W1t, 128, 256);
    k_wt<<<(256 * 128 / 8) / 256, 256, 0, stream>>>(W2, W2t, 256, 128);

    // CSR build + normalization (device-wide 3-stage scan)
    k_zero<<<NB, 256, 0, stream>>>(counts);
    k_hist<<<(N_EDGES + 255) / 256, 256, 0, stream>>>(dst, counts);
    k_blocksum<<<NB, 256, 0, stream>>>(counts, bsum);
    k_scanb<<<1, 256, 0, stream>>>(bsum, boff);
    k_scatter_rp<<<NB, 256, 0, stream>>>(counts, boff, row_ptr, fill, dinv);
    k_fill<<<(N_EDGES + 255) / 256, 256, 0, stream>>>(src, dst, fill, csr_src);

    // layer 1 (reordered): agg0_h = bf16(Agg(emb)); h_h = bf16(agg0 @ W1 + b1)
    k_gather128h<true><<<12500, 256, 0, stream>>>(emb_h, csr_src, row_ptr, dinv, nullptr, agg0_h);
    k_gemm_mfma<128, 256><<<N_NODES / 16, 256, 0, stream>>>((const ushort*)agg0_h, (const ushort*)W1t, b1, h_h);

    // layer 2: x2_h = bf16(h @ W2); out = Agg(x2) + b2
    k_gemm_mfma<256, 128><<<N_NODES / 16, 256, 0, stream>>>(h_h, (const ushort*)W2t, nullptr, x2_h);
    k_gather128h<false><<<12500, 256, 0, stream>>>((const uint*)x2_h, csr_src, row_ptr, dinv, b2, out);
}

// Round 9
// 159.915 us; speedup vs baseline: 1.9810x; 1.5772x over previous
//
#include <hip/hip_runtime.h>

#define N_NODES 50000
#define N_EDGES 800000
#define NB 196  // ceil(N_NODES / 256)

typedef unsigned int uint;
typedef short bf16x8 __attribute__((ext_vector_type(8)));
typedef float f32x4 __attribute__((ext_vector_type(4)));

__device__ __forceinline__ ushort f2bf(float f) {
    union { float f; uint u; } v; v.f = f;
    uint r = (v.u + 0x7FFFu + ((v.u >> 16) & 1u)) >> 16;  // RNE
    return (ushort)r;
}
__device__ __forceinline__ float bf_lo(uint u) { return __uint_as_float(u << 16); }
__device__ __forceinline__ float bf_hi(uint u) { return __uint_as_float(u & 0xFFFF0000u); }

// ---------- fp32 -> bf16 row-major copy (8 floats/thread) ----------
__global__ void k_tobf16(const float* __restrict__ in, uint* __restrict__ out) {
    int t = blockIdx.x * 256 + threadIdx.x;
    const float4* i4 = (const float4*)in + (size_t)t * 2;
    float4 v0 = i4[0], v1 = i4[1];
    uint4 o;
    o.x = (uint)f2bf(v0.x) | ((uint)f2bf(v0.y) << 16);
    o.y = (uint)f2bf(v0.z) | ((uint)f2bf(v0.w) << 16);
    o.z = (uint)f2bf(v1.x) | ((uint)f2bf(v1.y) << 16);
    o.w = (uint)f2bf(v1.z) | ((uint)f2bf(v1.w) << 16);
    ((uint4*)out)[t] = o;
}

// ---------- W12 = W1@W2 (bf16, transposed) and bvec = b1@W2 (fp32) ----------
// 129 blocks x 128 threads. Block k<128: W12t[n][k] = bf16(sum_m W1[k][m]W2[m][n]).
// Block 128: bvec[n] = sum_m b1[m]*W2[m][n].
__global__ void k_w12(const float* __restrict__ W1, const float* __restrict__ W2,
                      const float* __restrict__ b1, ushort* __restrict__ W12t,
                      float* __restrict__ bvec) {
    int n = threadIdx.x;
    int k = blockIdx.x;
    float s = 0.f;
    if (k < 128) {
        for (int m = 0; m < 256; ++m) s = fmaf(W1[(size_t)k * 256 + m], W2[(size_t)m * 128 + n], s);
        W12t[(size_t)n * 128 + k] = f2bf(s);
    } else {
        for (int m = 0; m < 256; ++m) s = fmaf(b1[m], W2[(size_t)m * 128 + n], s);
        bvec[n] = s;
    }
}

// ---------- degree / CSR build ----------

__global__ void k_zero(int* counts) {
    int i = blockIdx.x * 256 + threadIdx.x;
    if (i < N_NODES) counts[i] = 0;
}

// hist + per-edge rank (atomic return value). rank < ~64 << 65536.
__global__ void k_histrank(const int* __restrict__ dst, int* __restrict__ counts,
                           ushort* __restrict__ rank) {
    int e = blockIdx.x * 256 + threadIdx.x;
    if (e < N_EDGES) rank[e] = (ushort)atomicAdd(&counts[dst[e]], 1);
}

__global__ void k_blocksum(const int* __restrict__ counts, int* __restrict__ bsum) {
    __shared__ int lds[256];
    int t = threadIdx.x;
    int i = blockIdx.x * 256 + t;
    int v = (i < N_NODES) ? counts[i] : 0;
    lds[t] = v;
    __syncthreads();
    for (int off = 128; off > 0; off >>= 1) {
        if (t < off) lds[t] += lds[t + off];
        __syncthreads();
    }
    if (t == 0) bsum[blockIdx.x] = lds[0];
}

__global__ void k_scanb(const int* __restrict__ bsum, int* __restrict__ boff) {
    __shared__ int lds[256];
    int t = threadIdx.x;
    int v = (t < NB) ? bsum[t] : 0;
    lds[t] = v;
    __syncthreads();
    for (int off = 1; off < 256; off <<= 1) {
        int o = (t >= off) ? lds[t - off] : 0;
        __syncthreads();
        lds[t] += o;
        __syncthreads();
    }
    if (t < NB) boff[t] = lds[t] - v;  // exclusive
}

__global__ void k_scatter_rp(const int* __restrict__ counts, const int* __restrict__ boff,
                             int* __restrict__ row_ptr, float* __restrict__ dinv) {
    __shared__ int lds[256];
    int t = threadIdx.x;
    int i = blockIdx.x * 256 + t;
    int v = (i < N_NODES) ? counts[i] : 0;
    lds[t] = v;
    __syncthreads();
    for (int off = 1; off < 256; off <<= 1) {
        int o = (t >= off) ? lds[t - off] : 0;
        __syncthreads();
        lds[t] += o;
        __syncthreads();
    }
    if (i < N_NODES) {
        row_ptr[i] = boff[blockIdx.x] + lds[t] - v;
        dinv[i] = rsqrtf((float)(v + 1));  // +1 self-loop
    }
    if (i == 0) row_ptr[N_NODES] = N_EDGES;
}

// atomic-free CSR fill: pos = row_ptr[dst] + rank
__global__ void k_fillr(const int* __restrict__ src, const int* __restrict__ dst,
                        const ushort* __restrict__ rank, const int* __restrict__ row_ptr,
                        ushort* __restrict__ csr_src) {
    int e = blockIdx.x * 256 + threadIdx.x;
    if (e >= N_EDGES) return;
    int pos = row_ptr[dst[e]] + (int)rank[e];
    csr_src[pos] = (ushort)src[e];
}

// ---------- gather aggregation over bf16 table (F=128, one wave per dst) ----------
// out_bf16[d] = bf16( dinv[d]*sum_{s} dinv[s]*x[s] + dinv[d]^2*x[d] )
// 4 quarter-waves x 4-deep unroll = 16 rows in flight per wave.
// NVEC: also write nvec[d] = dinv[d]*sum_s dinv[s] + dinv[d]^2  (the N*1 vector).
template<bool NVEC>
__global__ void k_gather128h(const uint* __restrict__ xh, const ushort* __restrict__ csr,
                             const int* __restrict__ rp, const float* __restrict__ dinv,
                             uint* __restrict__ outp, float* __restrict__ nvec) {
    int node = blockIdx.x * 4 + (threadIdx.x >> 6);
    int lane = threadIdx.x & 63;
    int q = lane >> 4;
    int fl = lane & 15;
    int beg = rp[node], end = rp[node + 1];
    const uint4* xb = (const uint4*)xh;  // row s = 16 uint4s
    float a[8];
    #pragma unroll
    for (int i = 0; i < 8; ++i) a[i] = 0.f;
    float sc = 0.f;

    for (int j = beg + q; j < end; j += 16) {
        int j1 = j + 4, j2 = j + 8, j3 = j + 12;
        int s0 = csr[j];
        int s1 = (j1 < end) ? (int)csr[j1] : s0;
        int s2 = (j2 < end) ? (int)csr[j2] : s0;
        int s3 = (j3 < end) ? (int)csr[j3] : s0;
        float c0 = dinv[s0];
        float c1 = (j1 < end) ? dinv[s1] : 0.f;
        float c2 = (j2 < end) ? dinv[s2] : 0.f;
        float c3 = (j3 < end) ? dinv[s3] : 0.f;
        uint4 u0 = xb[(size_t)s0 * 16 + fl];
        uint4 u1 = xb[(size_t)s1 * 16 + fl];
        uint4 u2 = xb[(size_t)s2 * 16 + fl];
        uint4 u3 = xb[(size_t)s3 * 16 + fl];
        sc += c0 + c1 + c2 + c3;
        a[0] = fmaf(c0, bf_lo(u0.x), a[0]); a[1] = fmaf(c0, bf_hi(u0.x), a[1]);
        a[2] = fmaf(c0, bf_lo(u0.y), a[2]); a[3] = fmaf(c0, bf_hi(u0.y), a[3]);
        a[4] = fmaf(c0, bf_lo(u0.z), a[4]); a[5] = fmaf(c0, bf_hi(u0.z), a[5]);
        a[6] = fmaf(c0, bf_lo(u0.w), a[6]); a[7] = fmaf(c0, bf_hi(u0.w), a[7]);
        a[0] = fmaf(c1, bf_lo(u1.x), a[0]); a[1] = fmaf(c1, bf_hi(u1.x), a[1]);
        a[2] = fmaf(c1, bf_lo(u1.y), a[2]); a[3] = fmaf(c1, bf_hi(u1.y), a[3]);
        a[4] = fmaf(c1, bf_lo(u1.z), a[4]); a[5] = fmaf(c1, bf_hi(u1.z), a[5]);
        a[6] = fmaf(c1, bf_lo(u1.w), a[6]); a[7] = fmaf(c1, bf_hi(u1.w), a[7]);
        a[0] = fmaf(c2, bf_lo(u2.x), a[0]); a[1] = fmaf(c2, bf_hi(u2.x), a[1]);
        a[2] = fmaf(c2, bf_lo(u2.y), a[2]); a[3] = fmaf(c2, bf_hi(u2.y), a[3]);
        a[4] = fmaf(c2, bf_lo(u2.z), a[4]); a[5] = fmaf(c2, bf_hi(u2.z), a[5]);
        a[6] = fmaf(c2, bf_lo(u2.w), a[6]); a[7] = fmaf(c2, bf_hi(u2.w), a[7]);
        a[0] = fmaf(c3, bf_lo(u3.x), a[0]); a[1] = fmaf(c3, bf_hi(u3.x), a[1]);
        a[2] = fmaf(c3, bf_lo(u3.y), a[2]); a[3] = fmaf(c3, bf_hi(u3.y), a[3]);
        a[4] = fmaf(c3, bf_lo(u3.z), a[4]); a[5] = fmaf(c3, bf_hi(u3.z), a[5]);
        a[6] = fmaf(c3, bf_lo(u3.w), a[6]); a[7] = fmaf(c3, bf_hi(u3.w), a[7]);
    }
    #pragma unroll
    for (int off = 16; off < 64; off <<= 1) {
        #pragma unroll
        for (int i = 0; i < 8; ++i) a[i] += __shfl_xor(a[i], off);
        sc += __shfl_xor(sc, off);
    }
    if (q == 0) {
        float dd = dinv[node];
        float dd2 = dd * dd;
        uint4 u = xb[(size_t)node * 16 + fl];
        float s[8] = { bf_lo(u.x), bf_hi(u.x), bf_lo(u.y), bf_hi(u.y),
                       bf_lo(u.z), bf_hi(u.z), bf_lo(u.w), bf_hi(u.w) };
        uint4 p;
        float o0 = fmaf(dd, a[0], dd2 * s[0]), o1 = fmaf(dd, a[1], dd2 * s[1]);
        float o2 = fmaf(dd, a[2], dd2 * s[2]), o3 = fmaf(dd, a[3], dd2 * s[3]);
        float o4 = fmaf(dd, a[4], dd2 * s[4]), o5 = fmaf(dd, a[5], dd2 * s[5]);
        float o6 = fmaf(dd, a[6], dd2 * s[6]), o7 = fmaf(dd, a[7], dd2 * s[7]);
        p.x = (uint)f2bf(o0) | ((uint)f2bf(o1) << 16);
        p.y = (uint)f2bf(o2) | ((uint)f2bf(o3) << 16);
        p.z = (uint)f2bf(o4) | ((uint)f2bf(o5) << 16);
        p.w = (uint)f2bf(o6) | ((uint)f2bf(o7) << 16);
        ((uint4*)outp)[(size_t)node * 16 + fl] = p;
        if (NVEC && fl == 0) nvec[node] = fmaf(dd, sc, dd2);
    }
}

// ---------- final MFMA GEMM: out[16r][128] fp32 = G2[16r][128]bf16 @ W12t[128][128]
//            + nvec[r]*bvec[c] + b2[c] ----------
__global__ void __launch_bounds__(256)
k_gemm_out(const ushort* __restrict__ A, const ushort* __restrict__ Wt,
           const float* __restrict__ nvec, const float* __restrict__ bvec,
           const float* __restrict__ b2, float* __restrict__ out) {
    constexpr int K = 128, NC = 128, KC = 4, TPW = 2;
    const int lane = threadIdx.x & 63;
    const int wave = threadIdx.x >> 6;
    const int row0 = blockIdx.x * 16;
    const int r = row0 + (lane & 15);
    const int ksub = (lane >> 4) * 8;

    f32x4 acc[TPW];
    int col[TPW];
    #pragma unroll
    for (int t = 0; t < TPW; ++t) {
        acc[t] = (f32x4){0.f, 0.f, 0.f, 0.f};
        col[t] = (wave * TPW + t) * 16 + (lane & 15);
    }
    #pragma unroll
    for (int kc = 0; kc < KC; ++kc) {
        bf16x8 af = *(const bf16x8*)(A + (size_t)r * K + kc * 32 + ksub);
        #pragma unroll
        for (int t = 0; t < TPW; ++t) {
            bf16x8 bf = *(const bf16x8*)(Wt + (size_t)col[t] * K + kc * 32 + ksub);
            acc[t] = __builtin_amdgcn_mfma_f32_16x16x32_bf16(af, bf, acc[t], 0, 0, 0);
        }
    }
    const int rb = row0 + (lane >> 4) * 4;
    float nv[4];
    #pragma unroll
    for (int e = 0; e < 4; ++e) nv[e] = nvec[rb + e];
    #pragma unroll
    for (int t = 0; t < TPW; ++t) {
        float bv = bvec[col[t]];
        float bb = b2[col[t]];
        #pragma unroll
        for (int e = 0; e < 4; ++e) {
            out[(size_t)(rb + e) * NC + col[t]] = acc[t][e] + nv[e] * bv + bb;
        }
    }
}

extern "C" void kernel_launch(void* const* d_in, const int* in_sizes, int n_in,
                              void* d_out, int out_size, void* d_ws, size_t ws_size,
                              hipStream_t stream) {
    const float* emb = (const float*)d_in[0];   // [50000][128]
    const float* W1  = (const float*)d_in[1];   // [128][256]
    const float* b1  = (const float*)d_in[2];   // [256]
    const float* W2  = (const float*)d_in[3];   // [256][128]
    const float* b2  = (const float*)d_in[4];   // [128]
    const int*   ei  = (const int*)d_in[5];     // [2][800000]
    const int* src = ei;
    const int* dst = ei + N_EDGES;

    char* ws = (char*)d_ws;
    float*  dinv    = (float*) (ws);                    // 200 KB
    int*    counts  = (int*)   (ws + (256ull << 10));   // 200 KB
    int*    row_ptr = (int*)   (ws + (512ull << 10));   // 200 KB + 4
    int*    bsum    = (int*)   (ws + (768ull << 10));   // 784 B
    int*    boff    = (int*)   (ws + (772ull << 10));   // 784 B
    ushort* rank    = (ushort*)(ws + (1ull << 20));     // 1.6 MB  (1..2.6)
    ushort* csr_src = (ushort*)(ws + (3ull << 20));     // 1.6 MB  (3..4.6)
    ushort* W12t    = (ushort*)(ws + (5ull << 20));     // 32 KB
    float*  bvec    = (float*) (ws + (5ull << 20) + (64ull << 10));   // 512 B
    float*  nvec    = (float*) (ws + (5ull << 20) + (128ull << 10));  // 200 KB
    uint*   emb_h   = (uint*)  (ws + (6ull  << 20));    // 12.8 MB (6..18.8)
    uint*   G       = (uint*)  (ws + (19ull << 20));    // 12.8 MB (19..31.8)
    uint*   G2      = (uint*)  (ws + (32ull << 20));    // 12.8 MB (32..44.8)
    float*  out     = (float*)d_out;

    // independent precomputes
    k_tobf16<<<N_NODES * 128 / 8 / 256, 256, 0, stream>>>(emb, emb_h);
    k_w12<<<129, 128, 0, stream>>>(W1, W2, b1, W12t, bvec);

    // CSR build + normalization
    k_zero<<<NB, 256, 0, stream>>>(counts);
    k_histrank<<<(N_EDGES + 255) / 256, 256, 0, stream>>>(dst, counts, rank);
    k_blocksum<<<NB, 256, 0, stream>>>(counts, bsum);
    k_scanb<<<1, 256, 0, stream>>>(bsum, boff);
    k_scatter_rp<<<NB, 256, 0, stream>>>(counts, boff, row_ptr, dinv);
    k_fillr<<<(N_EDGES + 255) / 256, 256, 0, stream>>>(src, dst, rank, row_ptr, csr_src);

    // out = (N^2 emb) @ (W1W2) + (N·1) (b1W2) + b2
    k_gather128h<false><<<12500, 256, 0, stream>>>(emb_h, csr_src, row_ptr, dinv, G, nullptr);
    k_gather128h<true><<<12500, 256, 0, stream>>>(G, csr_src, row_ptr, dinv, G2, nvec);
    k_gemm_out<<<N_NODES / 16, 256, 0, stream>>>((const ushort*)G2, W12t, nvec, bvec, b2, out);
}